// Round 7
// baseline (828.255 us; speedup 1.0000x reference)
//
#include <hip/hip_runtime.h>
#include <hip/hip_cooperative_groups.h>
#include <cstdint>
#include <cstddef>

namespace cg = cooperative_groups;

typedef unsigned int uint;
typedef unsigned short ushort;

// bf16 helpers: RNE pack, shift-unpack (exact)
__device__ __forceinline__ ushort f2bf(float f) {
    uint u = __float_as_uint(f);
    u = u + 0x7FFFu + ((u >> 16) & 1u);
    return (ushort)(u >> 16);
}

// ---------------- CSR build: single cooperative kernel ----------------
// phases: zero -> count -> chunk-reduce -> scan(bsum) -> scan-write+dinv -> scatter

__global__ __launch_bounds__(256) void k_csr(const int* __restrict__ src,
                                             const int* __restrict__ dst,
                                             int* __restrict__ cnt,
                                             int* __restrict__ bsum,
                                             int* __restrict__ rowptr,
                                             int* __restrict__ cursor,
                                             float* __restrict__ dinv,
                                             int* __restrict__ esrc,
                                             int* __restrict__ pooled,
                                             int E, int N, int nchunks) {
    cg::grid_group grid = cg::this_grid();
    __shared__ int sd[256];
    const int tid = threadIdx.x;
    const int gid = blockIdx.x * 256 + tid;
    const int stride = gridDim.x * 256;

    // phase 0: zero cnt + pooled
    for (int i = gid; i < N; i += stride) cnt[i] = 0;
    if (gid < 128) pooled[gid] = 0;
    grid.sync();

    // phase 1: count in-degrees
    for (int e = gid; e < E; e += stride) atomicAdd(&cnt[dst[e]], 1);
    grid.sync();

    // phase 2: per-chunk (256 nodes) sums
    if (blockIdx.x < (uint)nchunks) {
        int i = blockIdx.x * 256 + tid;
        sd[tid] = (i < N) ? cnt[i] : 0;
        __syncthreads();
        for (int s = 128; s > 0; s >>= 1) {
            if (tid < s) sd[tid] += sd[tid + s];
            __syncthreads();
        }
        if (tid == 0) bsum[blockIdx.x] = sd[0];
    }
    grid.sync();

    // phase 3: exclusive scan of bsum (block 0; nchunks <= 256)
    if (blockIdx.x == 0) {
        int v = (tid < nchunks) ? bsum[tid] : 0;
        sd[tid] = v;
        __syncthreads();
        for (int off = 1; off < 256; off <<= 1) {
            int add = (tid >= off) ? sd[tid - off] : 0;
            __syncthreads();
            sd[tid] += add;
            __syncthreads();
        }
        if (tid < nchunks) bsum[tid] = sd[tid] - v;
    }
    grid.sync();

    // phase 4: in-chunk scan -> rowptr/cursor, plus dinv
    if (blockIdx.x < (uint)nchunks) {
        int i = blockIdx.x * 256 + tid;
        int v = (i < N) ? cnt[i] : 0;
        sd[tid] = v;
        __syncthreads();
        for (int off = 1; off < 256; off <<= 1) {
            int add = (tid >= off) ? sd[tid - off] : 0;
            __syncthreads();
            sd[tid] += add;
            __syncthreads();
        }
        int excl = sd[tid] - v + bsum[blockIdx.x];
        if (i < N) {
            rowptr[i] = excl;
            cursor[i] = excl;
            dinv[i] = rsqrtf((float)v + 1.0f);  // +1 self-loop, always > 0
        }
    }
    grid.sync();

    // phase 5: bucket scatter (CSR column list)
    for (int e = gid; e < E; e += stride) {
        int d = dst[e];
        int pos = atomicAdd(&cursor[d], 1);
        esrc[pos] = src[e];
    }
}

// ---------------- GEMM: C_bf16[n x 128] = A_f32[n x 128] @ W[128 x 128] ------
// 256 threads = 4 waves; tile 64 rows x 128 cols. K in 4 chunks of 32.
// A-chunk staged transposed As[k][row] (coalesced float4 reads), W-chunk flat.
// Thread (tr,tc): 4 rows x 8 cols, 32 FMA/k. Output packed bf16 (RNE).

#define AP 68  // padded pitch for As rows (floats)

__global__ __launch_bounds__(256, 4) void k_gemm128(const float* __restrict__ A,
                                                    const float* __restrict__ Wg,
                                                    ushort* __restrict__ C, int nrows) {
    __shared__ float As[32 * AP];    // [k][row]
    __shared__ float Ws[32 * 128];   // [k][col]
    const int tid = threadIdx.x;
    const int tc = tid & 15;         // 8 cols: tc*8 ..
    const int tr = tid >> 4;         // 4 rows: tr*4 ..
    const int r0 = blockIdx.x * 64;

    float acc[4][8];
#pragma unroll
    for (int j = 0; j < 4; j++)
#pragma unroll
        for (int c = 0; c < 8; c++) acc[j][c] = 0.0f;

    const float4* A4 = reinterpret_cast<const float4*>(A);
    const float4* Wg4 = reinterpret_cast<const float4*>(Wg);
    float4* Ws4 = reinterpret_cast<float4*>(Ws);

    const int srow = tid >> 3;       // 0..31 row within staging pass
    const int sk4 = tid & 7;         // float4 index within 32-k chunk

    for (int kc = 0; kc < 4; kc++) {
#pragma unroll
        for (int i = 0; i < 4; i++) Ws4[tid + 256 * i] = Wg4[kc * 1024 + tid + 256 * i];
#pragma unroll
        for (int pass = 0; pass < 2; pass++) {
            int rl = srow + pass * 32;
            int rg = r0 + rl;
            if (rg > nrows - 1) rg = nrows - 1;
            float4 av = A4[(size_t)rg * 32 + kc * 8 + sk4];
            int kb = sk4 * 4;
            As[(kb + 0) * AP + rl] = av.x;
            As[(kb + 1) * AP + rl] = av.y;
            As[(kb + 2) * AP + rl] = av.z;
            As[(kb + 3) * AP + rl] = av.w;
        }
        __syncthreads();

#pragma unroll 4
        for (int k = 0; k < 32; k++) {
            const float4 a = *reinterpret_cast<const float4*>(&As[k * AP + tr * 4]);
            const float4 w0 = *reinterpret_cast<const float4*>(&Ws[k * 128 + tc * 8]);
            const float4 w1 = *reinterpret_cast<const float4*>(&Ws[k * 128 + tc * 8 + 4]);
            const float av4[4] = {a.x, a.y, a.z, a.w};
            const float wv[8] = {w0.x, w0.y, w0.z, w0.w, w1.x, w1.y, w1.z, w1.w};
#pragma unroll
            for (int j = 0; j < 4; j++)
#pragma unroll
                for (int c = 0; c < 8; c++)
                    acc[j][c] = fmaf(av4[j], wv[c], acc[j][c]);
        }
        __syncthreads();
    }

#pragma unroll
    for (int j = 0; j < 4; j++) {
        const int r = r0 + tr * 4 + j;
        if (r < nrows) {
            uint4 o;
            o.x = (uint)f2bf(acc[j][0]) | ((uint)f2bf(acc[j][1]) << 16);
            o.y = (uint)f2bf(acc[j][2]) | ((uint)f2bf(acc[j][3]) << 16);
            o.z = (uint)f2bf(acc[j][4]) | ((uint)f2bf(acc[j][5]) << 16);
            o.w = (uint)f2bf(acc[j][6]) | ((uint)f2bf(acc[j][7]) << 16);
            *reinterpret_cast<uint4*>(&C[(size_t)r * 128 + tc * 8]) = o;
        }
    }
}

// ---------------- Gather (pull-style), bf16 rows ----------------
// one wave per dst node; lane owns cols (2*lane, 2*lane+1); row = 256 B bf16.
// edge loop unrolled x8. Accumulate fp32, write fp32 (layer-1 output).

__global__ __launch_bounds__(256) void k_gather(const ushort* __restrict__ hw,
                                                const float* __restrict__ dinv,
                                                const int* __restrict__ rowptr,
                                                const int* __restrict__ cnt,
                                                const int* __restrict__ esrc,
                                                const float* __restrict__ bias,
                                                float* __restrict__ outp, int n) {
    int wave = threadIdx.x >> 6;
    int lane = threadIdx.x & 63;
    int node = blockIdx.x * 4 + wave;
    if (node >= n) return;

    float di = dinv[node];
    int start = rowptr[node];
    int deg = cnt[node];

    const uint* base = reinterpret_cast<const uint*>(hw);
    uint vw = base[(size_t)node * 64 + lane];
    float vx = __uint_as_float((vw & 0xFFFFu) << 16);
    float vy = __uint_as_float(vw & 0xFFFF0000u);
    float sw = di * di;                 // self-loop weight
    float acc0 = vx * sw;
    float acc1 = vy * sw;

    int j = 0;
    for (; j + 7 < deg; j += 8) {
        int s[8]; float w[8]; uint u[8];
#pragma unroll
        for (int t = 0; t < 8; t++) s[t] = esrc[start + j + t];
#pragma unroll
        for (int t = 0; t < 8; t++) u[t] = base[(size_t)s[t] * 64 + lane];
#pragma unroll
        for (int t = 0; t < 8; t++) w[t] = dinv[s[t]] * di;
#pragma unroll
        for (int t = 0; t < 8; t++) {
            acc0 = fmaf(__uint_as_float((u[t] & 0xFFFFu) << 16), w[t], acc0);
            acc1 = fmaf(__uint_as_float(u[t] & 0xFFFF0000u), w[t], acc1);
        }
    }
    for (; j < deg; j++) {
        int s = esrc[start + j];
        float w = dinv[s] * di;
        uint u = base[(size_t)s * 64 + lane];
        acc0 = fmaf(__uint_as_float((u & 0xFFFFu) << 16), w, acc0);
        acc1 = fmaf(__uint_as_float(u & 0xFFFF0000u), w, acc1);
    }

    const float2* b2 = reinterpret_cast<const float2*>(bias);
    float2 bb = b2[lane];
    acc0 += bb.x;
    acc1 += bb.y;
    float2 o;
    o.x = acc0 > 0.0f ? acc0 : 0.0f;
    o.y = acc1 > 0.0f ? acc1 : 0.0f;
    reinterpret_cast<float2*>(outp + (size_t)node * 128)[lane] = o;
}

// ---------------- Gather #2 fused with max-pool (bf16 rows) ----------------

__global__ __launch_bounds__(256) void k_gather_pool(const ushort* __restrict__ hw,
                                                     const float* __restrict__ dinv,
                                                     const int* __restrict__ rowptr,
                                                     const int* __restrict__ cnt,
                                                     const int* __restrict__ esrc,
                                                     const float* __restrict__ bias,
                                                     int* __restrict__ pooledPart, int n) {
    __shared__ int smax[128];
    int tid = threadIdx.x;
    int wave = tid >> 6;
    int lane = tid & 63;
    if (tid < 128) smax[tid] = 0;
    __syncthreads();

    int node = blockIdx.x * 4 + wave;
    if (node < n) {
        float di = dinv[node];
        int start = rowptr[node];
        int deg = cnt[node];

        const uint* base = reinterpret_cast<const uint*>(hw);
        uint vw = base[(size_t)node * 64 + lane];
        float sw = di * di;
        float acc0 = __uint_as_float((vw & 0xFFFFu) << 16) * sw;
        float acc1 = __uint_as_float(vw & 0xFFFF0000u) * sw;

        int j = 0;
        for (; j + 7 < deg; j += 8) {
            int s[8]; float w[8]; uint u[8];
#pragma unroll
            for (int t = 0; t < 8; t++) s[t] = esrc[start + j + t];
#pragma unroll
            for (int t = 0; t < 8; t++) u[t] = base[(size_t)s[t] * 64 + lane];
#pragma unroll
            for (int t = 0; t < 8; t++) w[t] = dinv[s[t]] * di;
#pragma unroll
            for (int t = 0; t < 8; t++) {
                acc0 = fmaf(__uint_as_float((u[t] & 0xFFFFu) << 16), w[t], acc0);
                acc1 = fmaf(__uint_as_float(u[t] & 0xFFFF0000u), w[t], acc1);
            }
        }
        for (; j < deg; j++) {
            int s = esrc[start + j];
            float w = dinv[s] * di;
            uint u = base[(size_t)s * 64 + lane];
            acc0 = fmaf(__uint_as_float((u & 0xFFFFu) << 16), w, acc0);
            acc1 = fmaf(__uint_as_float(u & 0xFFFF0000u), w, acc1);
        }

        const float2* b2 = reinterpret_cast<const float2*>(bias);
        float2 bb = b2[lane];
        acc0 += bb.x;
        acc1 += bb.y;
        acc0 = acc0 > 0.0f ? acc0 : 0.0f;   // ReLU -> >= 0, int-compare trick valid
        acc1 = acc1 > 0.0f ? acc1 : 0.0f;
        atomicMax(&smax[lane * 2 + 0], __float_as_int(acc0));
        atomicMax(&smax[lane * 2 + 1], __float_as_int(acc1));
    }
    __syncthreads();
    if (tid < 128) pooledPart[(size_t)blockIdx.x * 128 + tid] = smax[tid];
}

// reduce partials: coalesced, then 128 global atomicMax per block

__global__ __launch_bounds__(256) void k_pool2(const int* __restrict__ pooledPart,
                                               int* __restrict__ pooledBits, int nPart) {
    __shared__ int smax[128];
    int tid = threadIdx.x;
    int c = tid & 127;
    int rh = tid >> 7;
    if (tid < 128) smax[tid] = 0;
    __syncthreads();
    int m = 0;
    for (int p = blockIdx.x * 2 + rh; p < nPart; p += gridDim.x * 2) {
        int v = pooledPart[(size_t)p * 128 + c];
        m = v > m ? v : m;   // post-ReLU bits: int compare == float compare
    }
    atomicMax(&smax[c], m);
    __syncthreads();
    if (tid < 128) atomicMax(&pooledBits[tid], smax[tid]);
}

__global__ __launch_bounds__(64) void k_fc(const int* __restrict__ pooledBits,
                                           const float* __restrict__ Wfc,
                                           const float* __restrict__ bfc,
                                           float* __restrict__ out) {
    int c = threadIdx.x;  // 0..63
    float acc = bfc[c];
    for (int k = 0; k < 128; k++)
        acc = fmaf(__int_as_float(pooledBits[k]), Wfc[k * 64 + c], acc);
    out[c] = acc;
}

// ---------------- launch ----------------

extern "C" void kernel_launch(void* const* d_in, const int* in_sizes, int n_in,
                              void* d_out, int out_size, void* d_ws, size_t ws_size,
                              hipStream_t stream) {
    const float* x   = (const float*)d_in[0];
    const int* edges = (const int*)d_in[1];
    const float* W1  = (const float*)d_in[2];
    const float* b1  = (const float*)d_in[3];
    const float* W2  = (const float*)d_in[4];
    const float* b2  = (const float*)d_in[5];
    const float* Wfc = (const float*)d_in[6];
    const float* bfc = (const float*)d_in[7];
    float* out = (float*)d_out;

    const int N = in_sizes[0] / 128;
    const int E = in_sizes[1] / 2;
    const int* esrc_in = edges;       // edge_index[0]
    const int* edst_in = edges + E;   // edge_index[1]

    // workspace layout (256B aligned chunks)
    auto align256 = [](size_t v) { return (v + 255) & ~(size_t)255; };
    char* p = (char*)d_ws;
    size_t off = 0;
    int* cnt      = (int*)(p + off); off = align256(off + (size_t)N * 4);
    int* rowptr   = (int*)(p + off); off = align256(off + (size_t)N * 4);
    int* cursor   = (int*)(p + off); off = align256(off + (size_t)N * 4);
    float* dinv   = (float*)(p + off); off = align256(off + (size_t)N * 4);
    int* bsum     = (int*)(p + off); off = align256(off + 256 * 4);
    int* pooled   = (int*)(p + off); off = align256(off + 128 * 4);
    int* esrc     = (int*)(p + off); off = align256(off + (size_t)E * 4);
    ushort* hwbuf = (ushort*)(p + off); off = align256(off + (size_t)N * 128 * 2);  // bf16 hw
    float* hbuf   = (float*)(p + off); off = align256(off + (size_t)N * 128 * 4);   // fp32 h1
    (void)ws_size; (void)n_in; (void)out_size;

    const int NCH = (N + 255) / 256;      // scan chunks (<=256)
    const int GB = (N + 63) / 64;         // gemm blocks (64 rows each)
    const int HB = (N + 3) / 4;           // gather blocks (4 nodes each)

    int* pooledPart = (int*)hbuf;         // reuse: 2nd gather no longer writes h

    // CSR build: one cooperative kernel (zero/count/scan/scatter)
    {
        int e = E, n = N, nch = NCH;
        void* args[] = {(void*)&esrc_in, (void*)&edst_in, (void*)&cnt, (void*)&bsum,
                        (void*)&rowptr, (void*)&cursor, (void*)&dinv, (void*)&esrc,
                        (void*)&pooled, (void*)&e, (void*)&n, (void*)&nch};
        hipLaunchCooperativeKernel((const void*)k_csr, dim3(1024), dim3(256), args, 0, stream);
    }

    // layer 1
    k_gemm128<<<GB, 256, 0, stream>>>(x, W1, hwbuf, N);
    k_gather<<<HB, 256, 0, stream>>>(hwbuf, dinv, rowptr, cnt, esrc, b1, hbuf, N);
    // layer 2
    k_gemm128<<<GB, 256, 0, stream>>>(hbuf, W2, hwbuf, N);
    k_gather_pool<<<HB, 256, 0, stream>>>(hwbuf, dinv, rowptr, cnt, esrc, b2, pooledPart, N);

    // pool reduce + fc
    k_pool2<<<128, 256, 0, stream>>>(pooledPart, pooled, HB);
    k_fc<<<1, 64, 0, stream>>>(pooled, Wfc, bfc, out);
}

// Round 8
// 364.802 us; speedup vs baseline: 2.2704x; 2.2704x over previous
//
#include <hip/hip_runtime.h>
#include <cstdint>
#include <cstddef>

typedef unsigned int uint;
typedef unsigned short ushort;

// bf16 helpers: RNE pack, shift-unpack (exact)
__device__ __forceinline__ ushort f2bf(float f) {
    uint u = __float_as_uint(f);
    u = u + 0x7FFFu + ((u >> 16) & 1u);
    return (ushort)(u >> 16);
}

// ---------------- CSR build (separate small kernels; coop grid.sync costs
// ~60-70us/barrier on MI355X — measured round 7 — so NO fusion here) --------

__global__ __launch_bounds__(256) void k_count(const int* __restrict__ dst,
                                               int* __restrict__ cnt, int E) {
    int e = blockIdx.x * 256 + threadIdx.x;
    if (e < E) atomicAdd(&cnt[dst[e]], 1);
}

__global__ __launch_bounds__(256) void k_block_reduce(const int* __restrict__ cnt,
                                                      int* __restrict__ bsum, int n) {
    __shared__ int sd[256];
    int i = blockIdx.x * 256 + threadIdx.x;
    sd[threadIdx.x] = (i < n) ? cnt[i] : 0;
    __syncthreads();
    for (int s = 128; s > 0; s >>= 1) {
        if (threadIdx.x < s) sd[threadIdx.x] += sd[threadIdx.x + s];
        __syncthreads();
    }
    if (threadIdx.x == 0) bsum[blockIdx.x] = sd[0];
}

// single block, nb <= 256: in-place exclusive scan of bsum
__global__ __launch_bounds__(256) void k_scan_bsum(int* __restrict__ bsum, int nb) {
    __shared__ int sd[256];
    int t = threadIdx.x;
    int v = (t < nb) ? bsum[t] : 0;
    sd[t] = v;
    __syncthreads();
    for (int off = 1; off < 256; off <<= 1) {
        int add = (t >= off) ? sd[t - off] : 0;
        __syncthreads();
        sd[t] += add;
        __syncthreads();
    }
    if (t < nb) bsum[t] = sd[t] - v;  // exclusive
}

// scan within block + add block offset; also emits dinv = rsqrt(deg+1)
__global__ __launch_bounds__(256) void k_scan_write(const int* __restrict__ cnt,
                                                    const int* __restrict__ bsum,
                                                    int* __restrict__ rowptr,
                                                    int* __restrict__ cursor,
                                                    float* __restrict__ dinv, int n) {
    __shared__ int sd[256];
    int t = threadIdx.x;
    int i = blockIdx.x * 256 + t;
    int v = (i < n) ? cnt[i] : 0;
    sd[t] = v;
    __syncthreads();
    for (int off = 1; off < 256; off <<= 1) {
        int add = (t >= off) ? sd[t - off] : 0;
        __syncthreads();
        sd[t] += add;
        __syncthreads();
    }
    int excl = sd[t] - v + bsum[blockIdx.x];
    if (i < n) {
        rowptr[i] = excl;
        cursor[i] = excl;
        dinv[i] = rsqrtf((float)v + 1.0f);  // +1 self-loop, always > 0
    }
}

__global__ __launch_bounds__(256) void k_scatter(const int* __restrict__ src,
                                                 const int* __restrict__ dst,
                                                 int* __restrict__ cursor,
                                                 int* __restrict__ esrc, int E) {
    int e = blockIdx.x * 256 + threadIdx.x;
    if (e < E) {
        int d = dst[e];
        int pos = atomicAdd(&cursor[d], 1);
        esrc[pos] = src[e];
    }
}

// ---------------- GEMM: C_bf16[n x 128] = A_f32[n x 128] @ W[128 x 128] ------
// 256 threads = 4 waves; tile 64 rows x 128 cols. K in 4 chunks of 32.
// A-chunk staged transposed As[k][row] (coalesced float4 reads), W-chunk flat.
// Thread (tr,tc): 4 rows x 8 cols, 32 FMA/k. Output packed bf16 (RNE).

#define AP 68  // padded pitch for As rows (floats)

__global__ __launch_bounds__(256, 4) void k_gemm128(const float* __restrict__ A,
                                                    const float* __restrict__ Wg,
                                                    ushort* __restrict__ C, int nrows) {
    __shared__ float As[32 * AP];    // [k][row]
    __shared__ float Ws[32 * 128];   // [k][col]
    const int tid = threadIdx.x;
    const int tc = tid & 15;         // 8 cols: tc*8 ..
    const int tr = tid >> 4;         // 4 rows: tr*4 ..
    const int r0 = blockIdx.x * 64;

    float acc[4][8];
#pragma unroll
    for (int j = 0; j < 4; j++)
#pragma unroll
        for (int c = 0; c < 8; c++) acc[j][c] = 0.0f;

    const float4* A4 = reinterpret_cast<const float4*>(A);
    const float4* Wg4 = reinterpret_cast<const float4*>(Wg);
    float4* Ws4 = reinterpret_cast<float4*>(Ws);

    const int srow = tid >> 3;       // 0..31 row within staging pass
    const int sk4 = tid & 7;         // float4 index within 32-k chunk

    for (int kc = 0; kc < 4; kc++) {
#pragma unroll
        for (int i = 0; i < 4; i++) Ws4[tid + 256 * i] = Wg4[kc * 1024 + tid + 256 * i];
#pragma unroll
        for (int pass = 0; pass < 2; pass++) {
            int rl = srow + pass * 32;
            int rg = r0 + rl;
            if (rg > nrows - 1) rg = nrows - 1;
            float4 av = A4[(size_t)rg * 32 + kc * 8 + sk4];
            int kb = sk4 * 4;
            As[(kb + 0) * AP + rl] = av.x;
            As[(kb + 1) * AP + rl] = av.y;
            As[(kb + 2) * AP + rl] = av.z;
            As[(kb + 3) * AP + rl] = av.w;
        }
        __syncthreads();

#pragma unroll 4
        for (int k = 0; k < 32; k++) {
            const float4 a = *reinterpret_cast<const float4*>(&As[k * AP + tr * 4]);
            const float4 w0 = *reinterpret_cast<const float4*>(&Ws[k * 128 + tc * 8]);
            const float4 w1 = *reinterpret_cast<const float4*>(&Ws[k * 128 + tc * 8 + 4]);
            const float av4[4] = {a.x, a.y, a.z, a.w};
            const float wv[8] = {w0.x, w0.y, w0.z, w0.w, w1.x, w1.y, w1.z, w1.w};
#pragma unroll
            for (int j = 0; j < 4; j++)
#pragma unroll
                for (int c = 0; c < 8; c++)
                    acc[j][c] = fmaf(av4[j], wv[c], acc[j][c]);
        }
        __syncthreads();
    }

#pragma unroll
    for (int j = 0; j < 4; j++) {
        const int r = r0 + tr * 4 + j;
        if (r < nrows) {
            uint4 o;
            o.x = (uint)f2bf(acc[j][0]) | ((uint)f2bf(acc[j][1]) << 16);
            o.y = (uint)f2bf(acc[j][2]) | ((uint)f2bf(acc[j][3]) << 16);
            o.z = (uint)f2bf(acc[j][4]) | ((uint)f2bf(acc[j][5]) << 16);
            o.w = (uint)f2bf(acc[j][6]) | ((uint)f2bf(acc[j][7]) << 16);
            *reinterpret_cast<uint4*>(&C[(size_t)r * 128 + tc * 8]) = o;
        }
    }
}

// ---------------- Gather (pull-style), bf16 rows ----------------
// one wave per dst node; lane owns cols (2*lane, 2*lane+1); row = 256 B bf16.
// edge loop unrolled x8. Accumulate fp32, write fp32 (layer-1 output).

__global__ __launch_bounds__(256) void k_gather(const ushort* __restrict__ hw,
                                                const float* __restrict__ dinv,
                                                const int* __restrict__ rowptr,
                                                const int* __restrict__ cnt,
                                                const int* __restrict__ esrc,
                                                const float* __restrict__ bias,
                                                float* __restrict__ outp, int n) {
    int wave = threadIdx.x >> 6;
    int lane = threadIdx.x & 63;
    int node = blockIdx.x * 4 + wave;
    if (node >= n) return;

    float di = dinv[node];
    int start = rowptr[node];
    int deg = cnt[node];

    const uint* base = reinterpret_cast<const uint*>(hw);
    uint vw = base[(size_t)node * 64 + lane];
    float vx = __uint_as_float((vw & 0xFFFFu) << 16);
    float vy = __uint_as_float(vw & 0xFFFF0000u);
    float sw = di * di;                 // self-loop weight
    float acc0 = vx * sw;
    float acc1 = vy * sw;

    int j = 0;
    for (; j + 7 < deg; j += 8) {
        int s[8]; float w[8]; uint u[8];
#pragma unroll
        for (int t = 0; t < 8; t++) s[t] = esrc[start + j + t];
#pragma unroll
        for (int t = 0; t < 8; t++) u[t] = base[(size_t)s[t] * 64 + lane];
#pragma unroll
        for (int t = 0; t < 8; t++) w[t] = dinv[s[t]] * di;
#pragma unroll
        for (int t = 0; t < 8; t++) {
            acc0 = fmaf(__uint_as_float((u[t] & 0xFFFFu) << 16), w[t], acc0);
            acc1 = fmaf(__uint_as_float(u[t] & 0xFFFF0000u), w[t], acc1);
        }
    }
    for (; j < deg; j++) {
        int s = esrc[start + j];
        float w = dinv[s] * di;
        uint u = base[(size_t)s * 64 + lane];
        acc0 = fmaf(__uint_as_float((u & 0xFFFFu) << 16), w, acc0);
        acc1 = fmaf(__uint_as_float(u & 0xFFFF0000u), w, acc1);
    }

    const float2* b2 = reinterpret_cast<const float2*>(bias);
    float2 bb = b2[lane];
    acc0 += bb.x;
    acc1 += bb.y;
    float2 o;
    o.x = acc0 > 0.0f ? acc0 : 0.0f;
    o.y = acc1 > 0.0f ? acc1 : 0.0f;
    reinterpret_cast<float2*>(outp + (size_t)node * 128)[lane] = o;
}

// ---------------- Gather #2 fused with max-pool (bf16 rows) ----------------

__global__ __launch_bounds__(256) void k_gather_pool(const ushort* __restrict__ hw,
                                                     const float* __restrict__ dinv,
                                                     const int* __restrict__ rowptr,
                                                     const int* __restrict__ cnt,
                                                     const int* __restrict__ esrc,
                                                     const float* __restrict__ bias,
                                                     int* __restrict__ pooledPart, int n) {
    __shared__ int smax[128];
    int tid = threadIdx.x;
    int wave = tid >> 6;
    int lane = tid & 63;
    if (tid < 128) smax[tid] = 0;
    __syncthreads();

    int node = blockIdx.x * 4 + wave;
    if (node < n) {
        float di = dinv[node];
        int start = rowptr[node];
        int deg = cnt[node];

        const uint* base = reinterpret_cast<const uint*>(hw);
        uint vw = base[(size_t)node * 64 + lane];
        float sw = di * di;
        float acc0 = __uint_as_float((vw & 0xFFFFu) << 16) * sw;
        float acc1 = __uint_as_float(vw & 0xFFFF0000u) * sw;

        int j = 0;
        for (; j + 7 < deg; j += 8) {
            int s[8]; float w[8]; uint u[8];
#pragma unroll
            for (int t = 0; t < 8; t++) s[t] = esrc[start + j + t];
#pragma unroll
            for (int t = 0; t < 8; t++) u[t] = base[(size_t)s[t] * 64 + lane];
#pragma unroll
            for (int t = 0; t < 8; t++) w[t] = dinv[s[t]] * di;
#pragma unroll
            for (int t = 0; t < 8; t++) {
                acc0 = fmaf(__uint_as_float((u[t] & 0xFFFFu) << 16), w[t], acc0);
                acc1 = fmaf(__uint_as_float(u[t] & 0xFFFF0000u), w[t], acc1);
            }
        }
        for (; j < deg; j++) {
            int s = esrc[start + j];
            float w = dinv[s] * di;
            uint u = base[(size_t)s * 64 + lane];
            acc0 = fmaf(__uint_as_float((u & 0xFFFFu) << 16), w, acc0);
            acc1 = fmaf(__uint_as_float(u & 0xFFFF0000u), w, acc1);
        }

        const float2* b2 = reinterpret_cast<const float2*>(bias);
        float2 bb = b2[lane];
        acc0 += bb.x;
        acc1 += bb.y;
        acc0 = acc0 > 0.0f ? acc0 : 0.0f;   // ReLU -> >= 0, int-compare trick valid
        acc1 = acc1 > 0.0f ? acc1 : 0.0f;
        atomicMax(&smax[lane * 2 + 0], __float_as_int(acc0));
        atomicMax(&smax[lane * 2 + 1], __float_as_int(acc1));
    }
    __syncthreads();
    if (tid < 128) pooledPart[(size_t)blockIdx.x * 128 + tid] = smax[tid];
}

// reduce partials: coalesced, then 128 global atomicMax per block

__global__ __launch_bounds__(256) void k_pool2(const int* __restrict__ pooledPart,
                                               int* __restrict__ pooledBits, int nPart) {
    __shared__ int smax[128];
    int tid = threadIdx.x;
    int c = tid & 127;
    int rh = tid >> 7;
    if (tid < 128) smax[tid] = 0;
    __syncthreads();
    int m = 0;
    for (int p = blockIdx.x * 2 + rh; p < nPart; p += gridDim.x * 2) {
        int v = pooledPart[(size_t)p * 128 + c];
        m = v > m ? v : m;   // post-ReLU bits: int compare == float compare
    }
    atomicMax(&smax[c], m);
    __syncthreads();
    if (tid < 128) atomicMax(&pooledBits[tid], smax[tid]);
}

__global__ __launch_bounds__(64) void k_fc(const int* __restrict__ pooledBits,
                                           const float* __restrict__ Wfc,
                                           const float* __restrict__ bfc,
                                           float* __restrict__ out) {
    int c = threadIdx.x;  // 0..63
    float acc = bfc[c];
    for (int k = 0; k < 128; k++)
        acc = fmaf(__int_as_float(pooledBits[k]), Wfc[k * 64 + c], acc);
    out[c] = acc;
}

// ---------------- launch ----------------

extern "C" void kernel_launch(void* const* d_in, const int* in_sizes, int n_in,
                              void* d_out, int out_size, void* d_ws, size_t ws_size,
                              hipStream_t stream) {
    const float* x   = (const float*)d_in[0];
    const int* edges = (const int*)d_in[1];
    const float* W1  = (const float*)d_in[2];
    const float* b1  = (const float*)d_in[3];
    const float* W2  = (const float*)d_in[4];
    const float* b2  = (const float*)d_in[5];
    const float* Wfc = (const float*)d_in[6];
    const float* bfc = (const float*)d_in[7];
    float* out = (float*)d_out;

    const int N = in_sizes[0] / 128;
    const int E = in_sizes[1] / 2;
    const int* esrc_in = edges;       // edge_index[0]
    const int* edst_in = edges + E;   // edge_index[1]

    // workspace layout (256B aligned chunks)
    auto align256 = [](size_t v) { return (v + 255) & ~(size_t)255; };
    char* p = (char*)d_ws;
    size_t off = 0;
    int* cnt      = (int*)(p + off); off = align256(off + (size_t)N * 4);
    int* rowptr   = (int*)(p + off); off = align256(off + (size_t)N * 4);
    int* cursor   = (int*)(p + off); off = align256(off + (size_t)N * 4);
    float* dinv   = (float*)(p + off); off = align256(off + (size_t)N * 4);
    int* bsum     = (int*)(p + off); off = align256(off + 256 * 4);
    int* pooled   = (int*)(p + off); off = align256(off + 128 * 4);
    int* esrc     = (int*)(p + off); off = align256(off + (size_t)E * 4);
    ushort* hwbuf = (ushort*)(p + off); off = align256(off + (size_t)N * 128 * 2);  // bf16 hw
    float* hbuf   = (float*)(p + off); off = align256(off + (size_t)N * 128 * 4);   // fp32 h1
    (void)ws_size; (void)n_in; (void)out_size;

    const int EB = (E + 255) / 256;       // edge blocks
    const int NB = (N + 255) / 256;       // node blocks (<=256 for single-block scan)
    const int GB = (N + 63) / 64;         // gemm blocks (64 rows each)
    const int HB = (N + 3) / 4;           // gather blocks (4 nodes each)

    int* pooledPart = (int*)hbuf;         // reuse: 2nd gather no longer writes h

    hipMemsetAsync(cnt, 0, (size_t)N * 4, stream);
    hipMemsetAsync(pooled, 0, 128 * 4, stream);

    k_count<<<EB, 256, 0, stream>>>(edst_in, cnt, E);
    k_block_reduce<<<NB, 256, 0, stream>>>(cnt, bsum, N);
    k_scan_bsum<<<1, 256, 0, stream>>>(bsum, NB);
    k_scan_write<<<NB, 256, 0, stream>>>(cnt, bsum, rowptr, cursor, dinv, N);
    k_scatter<<<EB, 256, 0, stream>>>(esrc_in, edst_in, cursor, esrc, E);

    // layer 1
    k_gemm128<<<GB, 256, 0, stream>>>(x, W1, hwbuf, N);
    k_gather<<<HB, 256, 0, stream>>>(hwbuf, dinv, rowptr, cnt, esrc, b1, hbuf, N);
    // layer 2
    k_gemm128<<<GB, 256, 0, stream>>>(hbuf, W2, hwbuf, N);
    k_gather_pool<<<HB, 256, 0, stream>>>(hwbuf, dinv, rowptr, cnt, esrc, b2, pooledPart, N);

    // pool reduce + fc
    k_pool2<<<128, 256, 0, stream>>>(pooledPart, pooled, HB);
    k_fc<<<1, 64, 0, stream>>>(pooled, Wfc, bfc, out);
}

// Round 9
// 320.945 us; speedup vs baseline: 2.5807x; 1.1367x over previous
//
#include <hip/hip_runtime.h>
#include <cstdint>
#include <cstddef>

typedef unsigned int uint;
typedef unsigned short ushort;

// bf16 helpers: RNE pack, shift-unpack (exact)
__device__ __forceinline__ ushort f2bf(float f) {
    uint u = __float_as_uint(f);
    u = u + 0x7FFFu + ((u >> 16) & 1u);
    return (ushort)(u >> 16);
}

// ---------------- CSR build ----------------
// (coop grid.sync costs ~60-70us/barrier on MI355X — measured round 7 — so
//  separate small kernels, NOT a fused cooperative kernel.)
// Rank trick: count's atomicAdd RETURN is the edge's rank within its dst
// bucket -> scatter needs no atomics (rowptr[d] + rank), breaking the
// atomic-roundtrip -> dependent-store chain that made scatter 57us (round 8).

__global__ __launch_bounds__(256) void k_count(const int* __restrict__ dst,
                                               int* __restrict__ cnt,
                                               int* __restrict__ rank, int E) {
    int e4 = (blockIdx.x * 256 + threadIdx.x) * 4;
    if (e4 + 3 < E) {
        int4 d = *reinterpret_cast<const int4*>(&dst[e4]);
        int4 r;
        r.x = atomicAdd(&cnt[d.x], 1);
        r.y = atomicAdd(&cnt[d.y], 1);
        r.z = atomicAdd(&cnt[d.z], 1);
        r.w = atomicAdd(&cnt[d.w], 1);
        *reinterpret_cast<int4*>(&rank[e4]) = r;   // coalesced 16B
    } else {
        for (int e = e4; e < E; e++)
            rank[e] = atomicAdd(&cnt[dst[e]], 1);
    }
}

__global__ __launch_bounds__(256) void k_block_reduce(const int* __restrict__ cnt,
                                                      int* __restrict__ bsum, int n) {
    __shared__ int sd[256];
    int i = blockIdx.x * 256 + threadIdx.x;
    sd[threadIdx.x] = (i < n) ? cnt[i] : 0;
    __syncthreads();
    for (int s = 128; s > 0; s >>= 1) {
        if (threadIdx.x < s) sd[threadIdx.x] += sd[threadIdx.x + s];
        __syncthreads();
    }
    if (threadIdx.x == 0) bsum[blockIdx.x] = sd[0];
}

// single block, nb <= 256: in-place exclusive scan of bsum
__global__ __launch_bounds__(256) void k_scan_bsum(int* __restrict__ bsum, int nb) {
    __shared__ int sd[256];
    int t = threadIdx.x;
    int v = (t < nb) ? bsum[t] : 0;
    sd[t] = v;
    __syncthreads();
    for (int off = 1; off < 256; off <<= 1) {
        int add = (t >= off) ? sd[t - off] : 0;
        __syncthreads();
        sd[t] += add;
        __syncthreads();
    }
    if (t < nb) bsum[t] = sd[t] - v;  // exclusive
}

// scan within block + add block offset; also emits dinv = rsqrt(deg+1)
__global__ __launch_bounds__(256) void k_scan_write(const int* __restrict__ cnt,
                                                    const int* __restrict__ bsum,
                                                    int* __restrict__ rowptr,
                                                    float* __restrict__ dinv, int n) {
    __shared__ int sd[256];
    int t = threadIdx.x;
    int i = blockIdx.x * 256 + t;
    int v = (i < n) ? cnt[i] : 0;
    sd[t] = v;
    __syncthreads();
    for (int off = 1; off < 256; off <<= 1) {
        int add = (t >= off) ? sd[t - off] : 0;
        __syncthreads();
        sd[t] += add;
        __syncthreads();
    }
    int excl = sd[t] - v + bsum[blockIdx.x];
    if (i < n) {
        rowptr[i] = excl;
        dinv[i] = rsqrtf((float)v + 1.0f);  // +1 self-loop, always > 0
    }
}

// no atomics: pos = rowptr[d] + rank[e]; rowptr is a hot read-only L2 table
__global__ __launch_bounds__(256) void k_scatter(const int* __restrict__ src,
                                                 const int* __restrict__ dst,
                                                 const int* __restrict__ rowptr,
                                                 const int* __restrict__ rank,
                                                 int* __restrict__ esrc, int E) {
    int e4 = (blockIdx.x * 256 + threadIdx.x) * 4;
    if (e4 + 3 < E) {
        int4 s = *reinterpret_cast<const int4*>(&src[e4]);
        int4 d = *reinterpret_cast<const int4*>(&dst[e4]);
        int4 r = *reinterpret_cast<const int4*>(&rank[e4]);
        esrc[rowptr[d.x] + r.x] = s.x;
        esrc[rowptr[d.y] + r.y] = s.y;
        esrc[rowptr[d.z] + r.z] = s.z;
        esrc[rowptr[d.w] + r.w] = s.w;
    } else {
        for (int e = e4; e < E; e++)
            esrc[rowptr[dst[e]] + rank[e]] = src[e];
    }
}

// ---------------- GEMM: C_bf16[n x 128] = A_f32[n x 128] @ W[128 x 128] ------
// 256 threads = 4 waves; tile 64 rows x 128 cols. K in 4 chunks of 32.
// A-chunk staged transposed As[k][row] (coalesced float4 reads), W-chunk flat.
// Thread (tr,tc): 4 rows x 8 cols, 32 FMA/k. Output packed bf16 (RNE).

#define AP 68  // padded pitch for As rows (floats)

__global__ __launch_bounds__(256, 4) void k_gemm128(const float* __restrict__ A,
                                                    const float* __restrict__ Wg,
                                                    ushort* __restrict__ C, int nrows) {
    __shared__ float As[32 * AP];    // [k][row]
    __shared__ float Ws[32 * 128];   // [k][col]
    const int tid = threadIdx.x;
    const int tc = tid & 15;         // 8 cols: tc*8 ..
    const int tr = tid >> 4;         // 4 rows: tr*4 ..
    const int r0 = blockIdx.x * 64;

    float acc[4][8];
#pragma unroll
    for (int j = 0; j < 4; j++)
#pragma unroll
        for (int c = 0; c < 8; c++) acc[j][c] = 0.0f;

    const float4* A4 = reinterpret_cast<const float4*>(A);
    const float4* Wg4 = reinterpret_cast<const float4*>(Wg);
    float4* Ws4 = reinterpret_cast<float4*>(Ws);

    const int srow = tid >> 3;       // 0..31 row within staging pass
    const int sk4 = tid & 7;         // float4 index within 32-k chunk

    for (int kc = 0; kc < 4; kc++) {
#pragma unroll
        for (int i = 0; i < 4; i++) Ws4[tid + 256 * i] = Wg4[kc * 1024 + tid + 256 * i];
#pragma unroll
        for (int pass = 0; pass < 2; pass++) {
            int rl = srow + pass * 32;
            int rg = r0 + rl;
            if (rg > nrows - 1) rg = nrows - 1;
            float4 av = A4[(size_t)rg * 32 + kc * 8 + sk4];
            int kb = sk4 * 4;
            As[(kb + 0) * AP + rl] = av.x;
            As[(kb + 1) * AP + rl] = av.y;
            As[(kb + 2) * AP + rl] = av.z;
            As[(kb + 3) * AP + rl] = av.w;
        }
        __syncthreads();

#pragma unroll 4
        for (int k = 0; k < 32; k++) {
            const float4 a = *reinterpret_cast<const float4*>(&As[k * AP + tr * 4]);
            const float4 w0 = *reinterpret_cast<const float4*>(&Ws[k * 128 + tc * 8]);
            const float4 w1 = *reinterpret_cast<const float4*>(&Ws[k * 128 + tc * 8 + 4]);
            const float av4[4] = {a.x, a.y, a.z, a.w};
            const float wv[8] = {w0.x, w0.y, w0.z, w0.w, w1.x, w1.y, w1.z, w1.w};
#pragma unroll
            for (int j = 0; j < 4; j++)
#pragma unroll
                for (int c = 0; c < 8; c++)
                    acc[j][c] = fmaf(av4[j], wv[c], acc[j][c]);
        }
        __syncthreads();
    }

#pragma unroll
    for (int j = 0; j < 4; j++) {
        const int r = r0 + tr * 4 + j;
        if (r < nrows) {
            uint4 o;
            o.x = (uint)f2bf(acc[j][0]) | ((uint)f2bf(acc[j][1]) << 16);
            o.y = (uint)f2bf(acc[j][2]) | ((uint)f2bf(acc[j][3]) << 16);
            o.z = (uint)f2bf(acc[j][4]) | ((uint)f2bf(acc[j][5]) << 16);
            o.w = (uint)f2bf(acc[j][6]) | ((uint)f2bf(acc[j][7]) << 16);
            *reinterpret_cast<uint4*>(&C[(size_t)r * 128 + tc * 8]) = o;
        }
    }
}

// ---------------- Gather (pull-style), bf16 rows ----------------
// one wave per dst node; lane owns cols (2*lane, 2*lane+1); row = 256 B bf16.
// edge loop unrolled x8. Accumulate fp32, write fp32 (layer-1 output).

__global__ __launch_bounds__(256) void k_gather(const ushort* __restrict__ hw,
                                                const float* __restrict__ dinv,
                                                const int* __restrict__ rowptr,
                                                const int* __restrict__ cnt,
                                                const int* __restrict__ esrc,
                                                const float* __restrict__ bias,
                                                float* __restrict__ outp, int n) {
    int wave = threadIdx.x >> 6;
    int lane = threadIdx.x & 63;
    int node = blockIdx.x * 4 + wave;
    if (node >= n) return;

    float di = dinv[node];
    int start = rowptr[node];
    int deg = cnt[node];

    const uint* base = reinterpret_cast<const uint*>(hw);
    uint vw = base[(size_t)node * 64 + lane];
    float vx = __uint_as_float((vw & 0xFFFFu) << 16);
    float vy = __uint_as_float(vw & 0xFFFF0000u);
    float sw = di * di;                 // self-loop weight
    float acc0 = vx * sw;
    float acc1 = vy * sw;

    int j = 0;
    for (; j + 7 < deg; j += 8) {
        int s[8]; float w[8]; uint u[8];
#pragma unroll
        for (int t = 0; t < 8; t++) s[t] = esrc[start + j + t];
#pragma unroll
        for (int t = 0; t < 8; t++) u[t] = base[(size_t)s[t] * 64 + lane];
#pragma unroll
        for (int t = 0; t < 8; t++) w[t] = dinv[s[t]] * di;
#pragma unroll
        for (int t = 0; t < 8; t++) {
            acc0 = fmaf(__uint_as_float((u[t] & 0xFFFFu) << 16), w[t], acc0);
            acc1 = fmaf(__uint_as_float(u[t] & 0xFFFF0000u), w[t], acc1);
        }
    }
    for (; j < deg; j++) {
        int s = esrc[start + j];
        float w = dinv[s] * di;
        uint u = base[(size_t)s * 64 + lane];
        acc0 = fmaf(__uint_as_float((u & 0xFFFFu) << 16), w, acc0);
        acc1 = fmaf(__uint_as_float(u & 0xFFFF0000u), w, acc1);
    }

    const float2* b2 = reinterpret_cast<const float2*>(bias);
    float2 bb = b2[lane];
    acc0 += bb.x;
    acc1 += bb.y;
    float2 o;
    o.x = acc0 > 0.0f ? acc0 : 0.0f;
    o.y = acc1 > 0.0f ? acc1 : 0.0f;
    reinterpret_cast<float2*>(outp + (size_t)node * 128)[lane] = o;
}

// ---------------- Gather #2 fused with max-pool (bf16 rows) ----------------

__global__ __launch_bounds__(256) void k_gather_pool(const ushort* __restrict__ hw,
                                                     const float* __restrict__ dinv,
                                                     const int* __restrict__ rowptr,
                                                     const int* __restrict__ cnt,
                                                     const int* __restrict__ esrc,
                                                     const float* __restrict__ bias,
                                                     int* __restrict__ pooledPart, int n) {
    __shared__ int smax[128];
    int tid = threadIdx.x;
    int wave = tid >> 6;
    int lane = tid & 63;
    if (tid < 128) smax[tid] = 0;
    __syncthreads();

    int node = blockIdx.x * 4 + wave;
    if (node < n) {
        float di = dinv[node];
        int start = rowptr[node];
        int deg = cnt[node];

        const uint* base = reinterpret_cast<const uint*>(hw);
        uint vw = base[(size_t)node * 64 + lane];
        float sw = di * di;
        float acc0 = __uint_as_float((vw & 0xFFFFu) << 16) * sw;
        float acc1 = __uint_as_float(vw & 0xFFFF0000u) * sw;

        int j = 0;
        for (; j + 7 < deg; j += 8) {
            int s[8]; float w[8]; uint u[8];
#pragma unroll
            for (int t = 0; t < 8; t++) s[t] = esrc[start + j + t];
#pragma unroll
            for (int t = 0; t < 8; t++) u[t] = base[(size_t)s[t] * 64 + lane];
#pragma unroll
            for (int t = 0; t < 8; t++) w[t] = dinv[s[t]] * di;
#pragma unroll
            for (int t = 0; t < 8; t++) {
                acc0 = fmaf(__uint_as_float((u[t] & 0xFFFFu) << 16), w[t], acc0);
                acc1 = fmaf(__uint_as_float(u[t] & 0xFFFF0000u), w[t], acc1);
            }
        }
        for (; j < deg; j++) {
            int s = esrc[start + j];
            float w = dinv[s] * di;
            uint u = base[(size_t)s * 64 + lane];
            acc0 = fmaf(__uint_as_float((u & 0xFFFFu) << 16), w, acc0);
            acc1 = fmaf(__uint_as_float(u & 0xFFFF0000u), w, acc1);
        }

        const float2* b2 = reinterpret_cast<const float2*>(bias);
        float2 bb = b2[lane];
        acc0 += bb.x;
        acc1 += bb.y;
        acc0 = acc0 > 0.0f ? acc0 : 0.0f;   // ReLU -> >= 0, int-compare trick valid
        acc1 = acc1 > 0.0f ? acc1 : 0.0f;
        atomicMax(&smax[lane * 2 + 0], __float_as_int(acc0));
        atomicMax(&smax[lane * 2 + 1], __float_as_int(acc1));
    }
    __syncthreads();
    if (tid < 128) pooledPart[(size_t)blockIdx.x * 128 + tid] = smax[tid];
}

// reduce partials: coalesced, then 128 global atomicMax per block

__global__ __launch_bounds__(256) void k_pool2(const int* __restrict__ pooledPart,
                                               int* __restrict__ pooledBits, int nPart) {
    __shared__ int smax[128];
    int tid = threadIdx.x;
    int c = tid & 127;
    int rh = tid >> 7;
    if (tid < 128) smax[tid] = 0;
    __syncthreads();
    int m = 0;
    for (int p = blockIdx.x * 2 + rh; p < nPart; p += gridDim.x * 2) {
        int v = pooledPart[(size_t)p * 128 + c];
        m = v > m ? v : m;   // post-ReLU bits: int compare == float compare
    }
    atomicMax(&smax[c], m);
    __syncthreads();
    if (tid < 128) atomicMax(&pooledBits[tid], smax[tid]);
}

__global__ __launch_bounds__(64) void k_fc(const int* __restrict__ pooledBits,
                                           const float* __restrict__ Wfc,
                                           const float* __restrict__ bfc,
                                           float* __restrict__ out) {
    int c = threadIdx.x;  // 0..63
    float acc = bfc[c];
    for (int k = 0; k < 128; k++)
        acc = fmaf(__int_as_float(pooledBits[k]), Wfc[k * 64 + c], acc);
    out[c] = acc;
}

// ---------------- launch ----------------

extern "C" void kernel_launch(void* const* d_in, const int* in_sizes, int n_in,
                              void* d_out, int out_size, void* d_ws, size_t ws_size,
                              hipStream_t stream) {
    const float* x   = (const float*)d_in[0];
    const int* edges = (const int*)d_in[1];
    const float* W1  = (const float*)d_in[2];
    const float* b1  = (const float*)d_in[3];
    const float* W2  = (const float*)d_in[4];
    const float* b2  = (const float*)d_in[5];
    const float* Wfc = (const float*)d_in[6];
    const float* bfc = (const float*)d_in[7];
    float* out = (float*)d_out;

    const int N = in_sizes[0] / 128;
    const int E = in_sizes[1] / 2;
    const int* esrc_in = edges;       // edge_index[0]
    const int* edst_in = edges + E;   // edge_index[1]

    // workspace layout (256B aligned chunks)
    auto align256 = [](size_t v) { return (v + 255) & ~(size_t)255; };
    char* p = (char*)d_ws;
    size_t off = 0;
    int* cnt      = (int*)(p + off); off = align256(off + (size_t)N * 4);
    int* rowptr   = (int*)(p + off); off = align256(off + (size_t)N * 4);
    int* rank     = (int*)(p + off); off = align256(off + (size_t)E * 4);
    float* dinv   = (float*)(p + off); off = align256(off + (size_t)N * 4);
    int* bsum     = (int*)(p + off); off = align256(off + 256 * 4);
    int* pooled   = (int*)(p + off); off = align256(off + 128 * 4);
    int* esrc     = (int*)(p + off); off = align256(off + (size_t)E * 4);
    ushort* hwbuf = (ushort*)(p + off); off = align256(off + (size_t)N * 128 * 2);  // bf16 hw
    float* hbuf   = (float*)(p + off); off = align256(off + (size_t)N * 128 * 4);   // fp32 h1
    (void)ws_size; (void)n_in; (void)out_size;

    const int EB4 = (E / 4 + 255) / 256;  // edge blocks, 4 edges/thread
    const int NB = (N + 255) / 256;       // node blocks (<=256 for single-block scan)
    const int GB = (N + 63) / 64;         // gemm blocks (64 rows each)
    const int HB = (N + 3) / 4;           // gather blocks (4 nodes each)

    int* pooledPart = (int*)hbuf;         // reuse: 2nd gather no longer writes h

    hipMemsetAsync(cnt, 0, (size_t)N * 4, stream);
    hipMemsetAsync(pooled, 0, 128 * 4, stream);

    k_count<<<EB4, 256, 0, stream>>>(edst_in, cnt, rank, E);
    k_block_reduce<<<NB, 256, 0, stream>>>(cnt, bsum, N);
    k_scan_bsum<<<1, 256, 0, stream>>>(bsum, NB);
    k_scan_write<<<NB, 256, 0, stream>>>(cnt, bsum, rowptr, dinv, N);
    k_scatter<<<EB4, 256, 0, stream>>>(esrc_in, edst_in, rowptr, rank, esrc, E);

    // layer 1
    k_gemm128<<<GB, 256, 0, stream>>>(x, W1, hwbuf, N);
    k_gather<<<HB, 256, 0, stream>>>(hwbuf, dinv, rowptr, cnt, esrc, b1, hbuf, N);
    // layer 2
    k_gemm128<<<GB, 256, 0, stream>>>(hbuf, W2, hwbuf, N);
    k_gather_pool<<<HB, 256, 0, stream>>>(hwbuf, dinv, rowptr, cnt, esrc, b2, pooledPart, N);

    // pool reduce + fc
    k_pool2<<<128, 256, 0, stream>>>(pooledPart, pooled, HB);
    k_fc<<<1, 64, 0, stream>>>(pooled, Wfc, bfc, out);
}

// Round 10
// 299.042 us; speedup vs baseline: 2.7697x; 1.0732x over previous
//
#include <hip/hip_runtime.h>
#include <cstdint>
#include <cstddef>

typedef unsigned int uint;
typedef unsigned short ushort;

// bf16 helpers: RNE pack, shift-unpack (exact)
__device__ __forceinline__ ushort f2bf(float f) {
    uint u = __float_as_uint(f);
    u = u + 0x7FFFu + ((u >> 16) & 1u);
    return (ushort)(u >> 16);
}
__device__ __forceinline__ float bf_lo(uint u) { return __uint_as_float((u & 0xFFFFu) << 16); }
__device__ __forceinline__ float bf_hi(uint u) { return __uint_as_float(u & 0xFFFF0000u); }

// ---------------- CSR build ----------------
// (coop grid.sync costs ~60-70us/barrier on MI355X — measured round 7 — so
//  separate small kernels, NOT a fused cooperative kernel.)
// Rank trick (round 9, -25us): count's atomicAdd RETURN is the edge's rank in
// its dst bucket -> scatter needs no atomics. Scatter also fuses the edge
// weight dinv[s]*dinv[d] into the CSR payload (int2 {src, w_bits}) so the
// gather's per-edge dinv load + mul disappears.

__global__ __launch_bounds__(256) void k_count(const int* __restrict__ dst,
                                               int* __restrict__ cnt,
                                               int* __restrict__ rank, int E) {
    int e4 = (blockIdx.x * 256 + threadIdx.x) * 4;
    if (e4 + 3 < E) {
        int4 d = *reinterpret_cast<const int4*>(&dst[e4]);
        int4 r;
        r.x = atomicAdd(&cnt[d.x], 1);
        r.y = atomicAdd(&cnt[d.y], 1);
        r.z = atomicAdd(&cnt[d.z], 1);
        r.w = atomicAdd(&cnt[d.w], 1);
        *reinterpret_cast<int4*>(&rank[e4]) = r;   // coalesced 16B
    } else {
        for (int e = e4; e < E; e++)
            rank[e] = atomicAdd(&cnt[dst[e]], 1);
    }
}

__global__ __launch_bounds__(256) void k_block_reduce(const int* __restrict__ cnt,
                                                      int* __restrict__ bsum, int n) {
    __shared__ int sd[256];
    int i = blockIdx.x * 256 + threadIdx.x;
    sd[threadIdx.x] = (i < n) ? cnt[i] : 0;
    __syncthreads();
    for (int s = 128; s > 0; s >>= 1) {
        if (threadIdx.x < s) sd[threadIdx.x] += sd[threadIdx.x + s];
        __syncthreads();
    }
    if (threadIdx.x == 0) bsum[blockIdx.x] = sd[0];
}

// block prefix (reduce bsum[0..bid) in LDS) + in-chunk scan + dinv.
// merges the old k_scan_bsum: bsum holds raw per-chunk sums. nb <= 256.
__global__ __launch_bounds__(256) void k_scan_write(const int* __restrict__ cnt,
                                                    const int* __restrict__ bsum,
                                                    int* __restrict__ rowptr,
                                                    float* __restrict__ dinv,
                                                    int n, int nb) {
    __shared__ int sd[256];
    int t = threadIdx.x;
    // 1) prefix = sum of bsum[0..blockIdx.x)
    sd[t] = (t < (int)blockIdx.x && t < nb) ? bsum[t] : 0;
    __syncthreads();
    for (int s = 128; s > 0; s >>= 1) {
        if (t < s) sd[t] += sd[t + s];
        __syncthreads();
    }
    int prefix = sd[0];
    __syncthreads();
    // 2) in-chunk exclusive scan
    int i = blockIdx.x * 256 + t;
    int v = (i < n) ? cnt[i] : 0;
    sd[t] = v;
    __syncthreads();
    for (int off = 1; off < 256; off <<= 1) {
        int add = (t >= off) ? sd[t - off] : 0;
        __syncthreads();
        sd[t] += add;
        __syncthreads();
    }
    int excl = sd[t] - v + prefix;
    if (i < n) {
        rowptr[i] = excl;
        dinv[i] = rsqrtf((float)v + 1.0f);  // +1 self-loop, always > 0
    }
}

// no atomics: pos = rowptr[d] + rank[e]; payload = {src, bits(dinv[s]*dinv[d])}
__global__ __launch_bounds__(256) void k_scatter(const int* __restrict__ src,
                                                 const int* __restrict__ dst,
                                                 const int* __restrict__ rowptr,
                                                 const int* __restrict__ rank,
                                                 const float* __restrict__ dinv,
                                                 int2* __restrict__ eSW, int E) {
    int e4 = (blockIdx.x * 256 + threadIdx.x) * 4;
    if (e4 + 3 < E) {
        int4 s = *reinterpret_cast<const int4*>(&src[e4]);
        int4 d = *reinterpret_cast<const int4*>(&dst[e4]);
        int4 r = *reinterpret_cast<const int4*>(&rank[e4]);
        int2 p0, p1, p2, p3;
        p0.x = s.x; p0.y = __float_as_int(dinv[s.x] * dinv[d.x]);
        p1.x = s.y; p1.y = __float_as_int(dinv[s.y] * dinv[d.y]);
        p2.x = s.z; p2.y = __float_as_int(dinv[s.z] * dinv[d.z]);
        p3.x = s.w; p3.y = __float_as_int(dinv[s.w] * dinv[d.w]);
        eSW[rowptr[d.x] + r.x] = p0;
        eSW[rowptr[d.y] + r.y] = p1;
        eSW[rowptr[d.z] + r.z] = p2;
        eSW[rowptr[d.w] + r.w] = p3;
    } else {
        for (int e = e4; e < E; e++) {
            int s = src[e], d = dst[e];
            int2 pp; pp.x = s; pp.y = __float_as_int(dinv[s] * dinv[d]);
            eSW[rowptr[d] + rank[e]] = pp;
        }
    }
}

// ---------------- GEMM: C_bf16[n x 128] = A_f32[n x 128] @ W[128 x 128] ------
// 256 threads = 4 waves; tile 64 rows x 128 cols. K in 4 chunks of 32.
// A-chunk staged transposed As[k][row] (coalesced float4 reads), W-chunk flat.
// Thread (tr,tc): 4 rows x 8 cols, 32 FMA/k. Output packed bf16 (RNE).

#define AP 68  // padded pitch for As rows (floats)

__global__ __launch_bounds__(256, 4) void k_gemm128(const float* __restrict__ A,
                                                    const float* __restrict__ Wg,
                                                    ushort* __restrict__ C, int nrows) {
    __shared__ float As[32 * AP];    // [k][row]
    __shared__ float Ws[32 * 128];   // [k][col]
    const int tid = threadIdx.x;
    const int tc = tid & 15;         // 8 cols: tc*8 ..
    const int tr = tid >> 4;         // 4 rows: tr*4 ..
    const int r0 = blockIdx.x * 64;

    float acc[4][8];
#pragma unroll
    for (int j = 0; j < 4; j++)
#pragma unroll
        for (int c = 0; c < 8; c++) acc[j][c] = 0.0f;

    const float4* A4 = reinterpret_cast<const float4*>(A);
    const float4* Wg4 = reinterpret_cast<const float4*>(Wg);
    float4* Ws4 = reinterpret_cast<float4*>(Ws);

    const int srow = tid >> 3;       // 0..31 row within staging pass
    const int sk4 = tid & 7;         // float4 index within 32-k chunk

    for (int kc = 0; kc < 4; kc++) {
#pragma unroll
        for (int i = 0; i < 4; i++) Ws4[tid + 256 * i] = Wg4[kc * 1024 + tid + 256 * i];
#pragma unroll
        for (int pass = 0; pass < 2; pass++) {
            int rl = srow + pass * 32;
            int rg = r0 + rl;
            if (rg > nrows - 1) rg = nrows - 1;
            float4 av = A4[(size_t)rg * 32 + kc * 8 + sk4];
            int kb = sk4 * 4;
            As[(kb + 0) * AP + rl] = av.x;
            As[(kb + 1) * AP + rl] = av.y;
            As[(kb + 2) * AP + rl] = av.z;
            As[(kb + 3) * AP + rl] = av.w;
        }
        __syncthreads();

#pragma unroll 4
        for (int k = 0; k < 32; k++) {
            const float4 a = *reinterpret_cast<const float4*>(&As[k * AP + tr * 4]);
            const float4 w0 = *reinterpret_cast<const float4*>(&Ws[k * 128 + tc * 8]);
            const float4 w1 = *reinterpret_cast<const float4*>(&Ws[k * 128 + tc * 8 + 4]);
            const float av4[4] = {a.x, a.y, a.z, a.w};
            const float wv[8] = {w0.x, w0.y, w0.z, w0.w, w1.x, w1.y, w1.z, w1.w};
#pragma unroll
            for (int j = 0; j < 4; j++)
#pragma unroll
                for (int c = 0; c < 8; c++)
                    acc[j][c] = fmaf(av4[j], wv[c], acc[j][c]);
        }
        __syncthreads();
    }

#pragma unroll
    for (int j = 0; j < 4; j++) {
        const int r = r0 + tr * 4 + j;
        if (r < nrows) {
            uint4 o;
            o.x = (uint)f2bf(acc[j][0]) | ((uint)f2bf(acc[j][1]) << 16);
            o.y = (uint)f2bf(acc[j][2]) | ((uint)f2bf(acc[j][3]) << 16);
            o.z = (uint)f2bf(acc[j][4]) | ((uint)f2bf(acc[j][5]) << 16);
            o.w = (uint)f2bf(acc[j][6]) | ((uint)f2bf(acc[j][7]) << 16);
            *reinterpret_cast<uint4*>(&C[(size_t)r * 128 + tc * 8]) = o;
        }
    }
}

// ---------------- Gather (pull-style), bf16 rows, half-wave pairing ---------
// wave = 1 dst node. lane = (half, sub): half 0 processes even edges, half 1
// odd edges; lane loads uint2 = 4 bf16 cols (sub*4..sub*4+3). One VMEM instr
// fetches TWO rows (512 B). Final __shfl_xor(32) combines halves.

__global__ __launch_bounds__(256) void k_gather(const ushort* __restrict__ hw,
                                                const float* __restrict__ dinv,
                                                const int* __restrict__ rowptr,
                                                const int* __restrict__ cnt,
                                                const int2* __restrict__ eSW,
                                                const float* __restrict__ bias,
                                                float* __restrict__ outp, int n) {
    int wave = threadIdx.x >> 6;
    int lane = threadIdx.x & 63;
    int half = lane >> 5;
    int sub = lane & 31;
    int node = blockIdx.x * 4 + wave;
    if (node >= n) return;

    float di = dinv[node];
    int start = rowptr[node];
    int deg = cnt[node];

    const uint2* base2 = reinterpret_cast<const uint2*>(hw);
    float a0, a1, a2, a3;
    {   // self-loop: half 0 only (half 1 weight 0)
        uint2 u = base2[(size_t)node * 32 + sub];
        float sw = half ? 0.0f : di * di;
        a0 = bf_lo(u.x) * sw; a1 = bf_hi(u.x) * sw;
        a2 = bf_lo(u.y) * sw; a3 = bf_hi(u.y) * sw;
    }

    int j = 0;
    for (; j + 8 <= deg; j += 8) {           // 4 full pairs, no predication
        int2 e[4]; uint2 u[4];
#pragma unroll
        for (int t = 0; t < 4; t++) e[t] = eSW[start + j + 2 * t + half];
#pragma unroll
        for (int t = 0; t < 4; t++) u[t] = base2[(size_t)e[t].x * 32 + sub];
#pragma unroll
        for (int t = 0; t < 4; t++) {
            float w = __int_as_float(e[t].y);
            a0 = fmaf(bf_lo(u[t].x), w, a0);
            a1 = fmaf(bf_hi(u[t].x), w, a1);
            a2 = fmaf(bf_lo(u[t].y), w, a2);
            a3 = fmaf(bf_hi(u[t].y), w, a3);
        }
    }
    for (; j < deg; j += 2) {                // tail pairs, predicated
        int idx = j + half;
        bool ok = idx < deg;
        int2 e = eSW[start + (ok ? idx : deg - 1)];
        float w = ok ? __int_as_float(e.y) : 0.0f;
        uint2 u = base2[(size_t)e.x * 32 + sub];
        a0 = fmaf(bf_lo(u.x), w, a0);
        a1 = fmaf(bf_hi(u.x), w, a1);
        a2 = fmaf(bf_lo(u.y), w, a2);
        a3 = fmaf(bf_hi(u.y), w, a3);
    }

    // combine halves
    a0 += __shfl_xor(a0, 32);
    a1 += __shfl_xor(a1, 32);
    a2 += __shfl_xor(a2, 32);
    a3 += __shfl_xor(a3, 32);

    if (half == 0) {
        float4 bb = reinterpret_cast<const float4*>(bias)[sub];
        float4 o;
        o.x = fmaxf(a0 + bb.x, 0.0f);
        o.y = fmaxf(a1 + bb.y, 0.0f);
        o.z = fmaxf(a2 + bb.z, 0.0f);
        o.w = fmaxf(a3 + bb.w, 0.0f);
        reinterpret_cast<float4*>(outp + (size_t)node * 128)[sub] = o;
    }
}

// ---------------- Gather #2 fused with max-pool (same structure) ------------

__global__ __launch_bounds__(256) void k_gather_pool(const ushort* __restrict__ hw,
                                                     const float* __restrict__ dinv,
                                                     const int* __restrict__ rowptr,
                                                     const int* __restrict__ cnt,
                                                     const int2* __restrict__ eSW,
                                                     const float* __restrict__ bias,
                                                     int* __restrict__ pooledPart, int n) {
    __shared__ int smax[128];
    int tid = threadIdx.x;
    int wave = tid >> 6;
    int lane = tid & 63;
    int half = lane >> 5;
    int sub = lane & 31;
    if (tid < 128) smax[tid] = 0;
    __syncthreads();

    int node = blockIdx.x * 4 + wave;
    if (node < n) {
        float di = dinv[node];
        int start = rowptr[node];
        int deg = cnt[node];

        const uint2* base2 = reinterpret_cast<const uint2*>(hw);
        float a0, a1, a2, a3;
        {
            uint2 u = base2[(size_t)node * 32 + sub];
            float sw = half ? 0.0f : di * di;
            a0 = bf_lo(u.x) * sw; a1 = bf_hi(u.x) * sw;
            a2 = bf_lo(u.y) * sw; a3 = bf_hi(u.y) * sw;
        }

        int j = 0;
        for (; j + 8 <= deg; j += 8) {
            int2 e[4]; uint2 u[4];
#pragma unroll
            for (int t = 0; t < 4; t++) e[t] = eSW[start + j + 2 * t + half];
#pragma unroll
            for (int t = 0; t < 4; t++) u[t] = base2[(size_t)e[t].x * 32 + sub];
#pragma unroll
            for (int t = 0; t < 4; t++) {
                float w = __int_as_float(e[t].y);
                a0 = fmaf(bf_lo(u[t].x), w, a0);
                a1 = fmaf(bf_hi(u[t].x), w, a1);
                a2 = fmaf(bf_lo(u[t].y), w, a2);
                a3 = fmaf(bf_hi(u[t].y), w, a3);
            }
        }
        for (; j < deg; j += 2) {
            int idx = j + half;
            bool ok = idx < deg;
            int2 e = eSW[start + (ok ? idx : deg - 1)];
            float w = ok ? __int_as_float(e.y) : 0.0f;
            uint2 u = base2[(size_t)e.x * 32 + sub];
            a0 = fmaf(bf_lo(u.x), w, a0);
            a1 = fmaf(bf_hi(u.x), w, a1);
            a2 = fmaf(bf_lo(u.y), w, a2);
            a3 = fmaf(bf_hi(u.y), w, a3);
        }

        a0 += __shfl_xor(a0, 32);
        a1 += __shfl_xor(a1, 32);
        a2 += __shfl_xor(a2, 32);
        a3 += __shfl_xor(a3, 32);

        if (half == 0) {
            float4 bb = reinterpret_cast<const float4*>(bias)[sub];
            a0 = fmaxf(a0 + bb.x, 0.0f);   // ReLU -> >= 0, int-max trick valid
            a1 = fmaxf(a1 + bb.y, 0.0f);
            a2 = fmaxf(a2 + bb.z, 0.0f);
            a3 = fmaxf(a3 + bb.w, 0.0f);
            atomicMax(&smax[sub * 4 + 0], __float_as_int(a0));
            atomicMax(&smax[sub * 4 + 1], __float_as_int(a1));
            atomicMax(&smax[sub * 4 + 2], __float_as_int(a2));
            atomicMax(&smax[sub * 4 + 3], __float_as_int(a3));
        }
    }
    __syncthreads();
    if (tid < 128) pooledPart[(size_t)blockIdx.x * 128 + tid] = smax[tid];
}

// reduce partials: coalesced, then 128 global atomicMax per block.
// pooledBits needs NO memset: 0xAA poison = negative int, all values >= 0 win.

__global__ __launch_bounds__(256) void k_pool2(const int* __restrict__ pooledPart,
                                               int* __restrict__ pooledBits, int nPart) {
    __shared__ int smax[128];
    int tid = threadIdx.x;
    int c = tid & 127;
    int rh = tid >> 7;
    if (tid < 128) smax[tid] = 0;
    __syncthreads();
    int m = 0;
    for (int p = blockIdx.x * 2 + rh; p < nPart; p += gridDim.x * 2) {
        int v = pooledPart[(size_t)p * 128 + c];
        m = v > m ? v : m;   // post-ReLU bits: int compare == float compare
    }
    atomicMax(&smax[c], m);
    __syncthreads();
    if (tid < 128) atomicMax(&pooledBits[tid], smax[tid]);
}

__global__ __launch_bounds__(64) void k_fc(const int* __restrict__ pooledBits,
                                           const float* __restrict__ Wfc,
                                           const float* __restrict__ bfc,
                                           float* __restrict__ out) {
    int c = threadIdx.x;  // 0..63
    float acc = bfc[c];
    for (int k = 0; k < 128; k++)
        acc = fmaf(__int_as_float(pooledBits[k]), Wfc[k * 64 + c], acc);
    out[c] = acc;
}

// ---------------- launch ----------------

extern "C" void kernel_launch(void* const* d_in, const int* in_sizes, int n_in,
                              void* d_out, int out_size, void* d_ws, size_t ws_size,
                              hipStream_t stream) {
    const float* x   = (const float*)d_in[0];
    const int* edges = (const int*)d_in[1];
    const float* W1  = (const float*)d_in[2];
    const float* b1  = (const float*)d_in[3];
    const float* W2  = (const float*)d_in[4];
    const float* b2  = (const float*)d_in[5];
    const float* Wfc = (const float*)d_in[6];
    const float* bfc = (const float*)d_in[7];
    float* out = (float*)d_out;

    const int N = in_sizes[0] / 128;
    const int E = in_sizes[1] / 2;
    const int* esrc_in = edges;       // edge_index[0]
    const int* edst_in = edges + E;   // edge_index[1]

    // workspace layout (256B aligned chunks)
    auto align256 = [](size_t v) { return (v + 255) & ~(size_t)255; };
    char* p = (char*)d_ws;
    size_t off = 0;
    int* cnt      = (int*)(p + off); off = align256(off + (size_t)N * 4);
    int* rowptr   = (int*)(p + off); off = align256(off + (size_t)N * 4);
    int* rank     = (int*)(p + off); off = align256(off + (size_t)E * 4);
    float* dinv   = (float*)(p + off); off = align256(off + (size_t)N * 4);
    int* bsum     = (int*)(p + off); off = align256(off + 256 * 4);
    int* pooled   = (int*)(p + off); off = align256(off + 128 * 4);
    int2* eSW     = (int2*)(p + off); off = align256(off + (size_t)E * 8);
    ushort* hwbuf = (ushort*)(p + off); off = align256(off + (size_t)N * 128 * 2);  // bf16 hw
    float* hbuf   = (float*)(p + off); off = align256(off + (size_t)N * 128 * 4);   // fp32 h1
    (void)ws_size; (void)n_in; (void)out_size;

    const int EB4 = (E / 4 + 255) / 256;  // edge blocks, 4 edges/thread
    const int NB = (N + 255) / 256;       // node blocks (<=256 for single-block scan)
    const int GB = (N + 63) / 64;         // gemm blocks (64 rows each)
    const int HB = (N + 3) / 4;           // gather blocks (4 nodes each)

    int* pooledPart = (int*)hbuf;         // reuse: 2nd gather no longer writes h

    hipMemsetAsync(cnt, 0, (size_t)N * 4, stream);

    k_count<<<EB4, 256, 0, stream>>>(edst_in, cnt, rank, E);
    k_block_reduce<<<NB, 256, 0, stream>>>(cnt, bsum, N);
    k_scan_write<<<NB, 256, 0, stream>>>(cnt, bsum, rowptr, dinv, N, NB);
    k_scatter<<<EB4, 256, 0, stream>>>(esrc_in, edst_in, rowptr, rank, dinv, eSW, E);

    // layer 1
    k_gemm128<<<GB, 256, 0, stream>>>(x, W1, hwbuf, N);
    k_gather<<<HB, 256, 0, stream>>>(hwbuf, dinv, rowptr, cnt, eSW, b1, hbuf, N);
    // layer 2
    k_gemm128<<<GB, 256, 0, stream>>>(hbuf, W2, hwbuf, N);
    k_gather_pool<<<HB, 256, 0, stream>>>(hwbuf, dinv, rowptr, cnt, eSW, b2, pooledPart, N);

    // pool reduce + fc
    k_pool2<<<128, 256, 0, stream>>>(pooledPart, pooled, HB);
    k_fc<<<1, 64, 0, stream>>>(pooled, Wfc, bfc, out);
}